// Round 1
// baseline (37.849 us; speedup 1.0000x reference)
//
#include <hip/hip_runtime.h>

// Problem geometry (from reference): pred/target are (32, 3, 512, 512) f32.
// V = max_c(clip(x,0,1)) = clip(max_c(x),0,1); loss = mean |Vp - Vt| over 32*512*512.
#define HW      (512 * 512)          // per-channel plane, 262144 elements
#define NPIX    (32 * HW)            // 8388608 pixels
#define NVEC    (NPIX / 4)           // float4-vectorized pixel count
#define NBLOCKS 2048
#define NTHREADS 256

__device__ __forceinline__ float vmax3_clamp(float r, float g, float b) {
    float m = fmaxf(fmaxf(r, g), b);          // compiler emits v_max3_f32
    return fminf(fmaxf(m, 0.0f), 1.0f);       // clip commutes with max
}

__global__ __launch_bounds__(NTHREADS) void brightness_l1_partial(
    const float* __restrict__ pred,
    const float* __restrict__ target,
    float* __restrict__ partials) {
    int tid = blockIdx.x * blockDim.x + threadIdx.x;
    const int stride = NBLOCKS * NTHREADS;

    float acc = 0.0f;
    for (int i = tid; i < NVEC; i += stride) {
        int p  = i << 2;               // scalar pixel index (vec4 aligned)
        int n  = p >> 18;              // p / HW   (HW = 2^18)
        int hw = p & (HW - 1);         // p % HW
        size_t base = (size_t)n * (3 * HW) + hw;

        const float4 pr = *reinterpret_cast<const float4*>(pred + base);
        const float4 pg = *reinterpret_cast<const float4*>(pred + base + HW);
        const float4 pb = *reinterpret_cast<const float4*>(pred + base + 2 * HW);
        const float4 tr = *reinterpret_cast<const float4*>(target + base);
        const float4 tg = *reinterpret_cast<const float4*>(target + base + HW);
        const float4 tb = *reinterpret_cast<const float4*>(target + base + 2 * HW);

        acc += fabsf(vmax3_clamp(pr.x, pg.x, pb.x) - vmax3_clamp(tr.x, tg.x, tb.x));
        acc += fabsf(vmax3_clamp(pr.y, pg.y, pb.y) - vmax3_clamp(tr.y, tg.y, tb.y));
        acc += fabsf(vmax3_clamp(pr.z, pg.z, pb.z) - vmax3_clamp(tr.z, tg.z, tb.z));
        acc += fabsf(vmax3_clamp(pr.w, pg.w, pb.w) - vmax3_clamp(tr.w, tg.w, tb.w));
    }

    // wave64 tree reduce
    #pragma unroll
    for (int off = 32; off > 0; off >>= 1)
        acc += __shfl_down(acc, off, 64);

    __shared__ float smem[NTHREADS / 64];
    int lane = threadIdx.x & 63;
    int wave = threadIdx.x >> 6;
    if (lane == 0) smem[wave] = acc;
    __syncthreads();
    if (threadIdx.x == 0) {
        float s = smem[0];
        #pragma unroll
        for (int w = 1; w < NTHREADS / 64; ++w) s += smem[w];
        partials[blockIdx.x] = s;
    }
}

__global__ __launch_bounds__(NTHREADS) void brightness_l1_finalize(
    const float* __restrict__ partials,
    float* __restrict__ out) {
    float acc = 0.0f;
    for (int i = threadIdx.x; i < NBLOCKS; i += NTHREADS)
        acc += partials[i];

    #pragma unroll
    for (int off = 32; off > 0; off >>= 1)
        acc += __shfl_down(acc, off, 64);

    __shared__ float smem[NTHREADS / 64];
    int lane = threadIdx.x & 63;
    int wave = threadIdx.x >> 6;
    if (lane == 0) smem[wave] = acc;
    __syncthreads();
    if (threadIdx.x == 0) {
        float s = smem[0];
        #pragma unroll
        for (int w = 1; w < NTHREADS / 64; ++w) s += smem[w];
        out[0] = s * (1.0f / (float)NPIX);
    }
}

extern "C" void kernel_launch(void* const* d_in, const int* in_sizes, int n_in,
                              void* d_out, int out_size, void* d_ws, size_t ws_size,
                              hipStream_t stream) {
    const float* pred   = (const float*)d_in[0];
    const float* target = (const float*)d_in[1];
    float* out      = (float*)d_out;
    float* partials = (float*)d_ws;   // NBLOCKS floats = 8 KiB scratch

    brightness_l1_partial<<<NBLOCKS, NTHREADS, 0, stream>>>(pred, target, partials);
    brightness_l1_finalize<<<1, NTHREADS, 0, stream>>>(partials, out);
}